// Round 1
// baseline (1114.005 us; speedup 1.0000x reference)
//
#include <hip/hip_runtime.h>
#include <hip/hip_bf16.h>
#include <math.h>

// Problem constants
#define B_    8
#define S_    512
#define H_    768
#define HID_  384
#define G3_   1152      // 3*HID
#define ENT_  52
#define INNER_ 64
#define NOUT_ 6656      // ENT*2*INNER
#define K1_   1536
#define KA_   768       // lhs part of K
#define BIG_  1000000000000.0f

// ---------------------------------------------------------------------------
// Kernel 0: RoPE cos/sin table: tab[s][i] = {cos(s*invf_i), sin(s*invf_i)},
// i in [0,32), invf_i = 10000^(-2i/64)
// ---------------------------------------------------------------------------
__global__ void rope_table_k(float* __restrict__ tab) {
    int idx = blockIdx.x * blockDim.x + threadIdx.x;   // 512*32 total
    if (idx >= S_ * 32) return;
    int s = idx >> 5;
    int i = idx & 31;
    float t = -2.0f * (float)i / 64.0f;
    float invf = powf(10000.0f, t);
    float ang = (float)s * invf;
    tab[idx * 2 + 0] = cosf(ang);
    tab[idx * 2 + 1] = sinf(ang);
}

// ---------------------------------------------------------------------------
// Kernel 1: GRU input/hidden GEMMs. One wave per (dir, j) computes
//   gi[dir][b][j] = dot(cls[b], w_ih[j]) + b_ih[j]   (K=768)
//   gh[dir][b][j] = dot(h0[dir][b], w_hh[j]) + b_hh[j] (K=384)
// ---------------------------------------------------------------------------
__global__ void gru_gemm_k(const float* __restrict__ cls,
                           const float* __restrict__ h0,
                           const float* __restrict__ wihf, const float* __restrict__ whhf,
                           const float* __restrict__ bihf, const float* __restrict__ bhhf,
                           const float* __restrict__ wihb, const float* __restrict__ whhb,
                           const float* __restrict__ bihb, const float* __restrict__ bhhb,
                           float* __restrict__ gi, float* __restrict__ gh) {
    int wave = blockIdx.x * (blockDim.x >> 6) + (threadIdx.x >> 6);
    int lane = threadIdx.x & 63;
    if (wave >= 2 * G3_) return;
    int dir = wave / G3_;
    int j = wave % G3_;
    const float* wih = dir ? wihb : wihf;
    const float* whh = dir ? whhb : whhf;
    const float* bih = dir ? bihb : bihf;
    const float* bhh = dir ? bhhb : bhhf;

    float ai[B_], ah[B_];
#pragma unroll
    for (int b = 0; b < B_; ++b) { ai[b] = 0.f; ah[b] = 0.f; }

    for (int k = lane; k < H_; k += 64) {
        float w = wih[j * H_ + k];
#pragma unroll
        for (int b = 0; b < B_; ++b) ai[b] += w * cls[b * H_ + k];
    }
    for (int k = lane; k < HID_; k += 64) {
        float w = whh[j * HID_ + k];
#pragma unroll
        for (int b = 0; b < B_; ++b) ah[b] += w * h0[(dir * B_ + b) * HID_ + k];
    }
#pragma unroll
    for (int off = 32; off > 0; off >>= 1) {
#pragma unroll
        for (int b = 0; b < B_; ++b) {
            ai[b] += __shfl_xor(ai[b], off);
            ah[b] += __shfl_xor(ah[b], off);
        }
    }
    if (lane == 0) {
#pragma unroll
        for (int b = 0; b < B_; ++b) {
            gi[(dir * B_ + b) * G3_ + j] = ai[b] + bih[j];
            gh[(dir * B_ + b) * G3_ + j] = ah[b] + bhh[j];
        }
    }
}

// ---------------------------------------------------------------------------
// Kernel 2: GRU gate nonlinearities -> cls_emb (8 x 768), fwd||bwd concat.
// ---------------------------------------------------------------------------
__global__ void gru_combine_k(const float* __restrict__ gi, const float* __restrict__ gh,
                              const float* __restrict__ h0, float* __restrict__ cls_emb) {
    int idx = blockIdx.x * blockDim.x + threadIdx.x;   // 2*8*384
    if (idx >= 2 * B_ * HID_) return;
    int dir = idx / (B_ * HID_);
    int r = idx % (B_ * HID_);
    int b = r / HID_;
    int h = r % HID_;
    const float* giP = gi + (dir * B_ + b) * G3_;
    const float* ghP = gh + (dir * B_ + b) * G3_;
    float ir = giP[h],        hr = ghP[h];
    float iz = giP[HID_ + h], hz = ghP[HID_ + h];
    float in_ = giP[2 * HID_ + h], hn = ghP[2 * HID_ + h];
    float rr = 1.f / (1.f + expf(-(ir + hr)));
    float z  = 1.f / (1.f + expf(-(iz + hz)));
    float n  = tanhf(in_ + rr * hn);
    float hp = h0[(dir * B_ + b) * HID_ + h];
    cls_emb[b * H_ + dir * HID_ + h] = (1.f - z) * n + z * hp;
}

// ---------------------------------------------------------------------------
// Kernel 3a: cls contribution GEMV: ctr[b][n] = dot(cls_emb[b], dense_w[n][768:]) + dense_b[n]
// One wave per n.
// ---------------------------------------------------------------------------
__global__ void cls_ctr_k(const float* __restrict__ cls_emb,
                          const float* __restrict__ dw, const float* __restrict__ db,
                          float* __restrict__ ctr) {
    int wave = blockIdx.x * (blockDim.x >> 6) + (threadIdx.x >> 6);
    int lane = threadIdx.x & 63;
    if (wave >= NOUT_) return;
    const float* w = dw + (size_t)wave * K1_ + KA_;
    float a[B_];
#pragma unroll
    for (int b = 0; b < B_; ++b) a[b] = 0.f;
    for (int k = lane; k < H_; k += 64) {
        float ww = w[k];
#pragma unroll
        for (int b = 0; b < B_; ++b) a[b] += ww * cls_emb[b * H_ + k];
    }
#pragma unroll
    for (int off = 32; off > 0; off >>= 1) {
#pragma unroll
        for (int b = 0; b < B_; ++b) a[b] += __shfl_xor(a[b], off);
    }
    if (lane == 0) {
#pragma unroll
        for (int b = 0; b < B_; ++b) ctr[b * NOUT_ + wave] = a[b] + db[wave];
    }
}

// ---------------------------------------------------------------------------
// Kernel 3b: main dense GEMM (M=4096, N=6656, K=768) with fused cls-add +
// RoPE epilogue. 128x128 tile, BK=16, 256 threads, 8x8 per thread.
// Writes rotated q/k panels: q_ws/k_ws[b][ent][s][d] (d in [0,64)).
// Grid: (52, 32) = (ent tile, m tile).
// ---------------------------------------------------------------------------
__global__ __launch_bounds__(256)
void dense_gemm_k(const float* __restrict__ lhs,      // (8,512,768)
                  const float* __restrict__ dw,       // (6656,1536)
                  const float* __restrict__ ctr,      // (8,6656)
                  const float* __restrict__ rope,     // (512,32,2)
                  float* __restrict__ q_ws, float* __restrict__ k_ws) {
    __shared__ float As[16][132];
    __shared__ float Bs[16][132];

    int tid = threadIdx.x;
    int tx = tid & 15;           // n dimension
    int ty = tid >> 4;           // m dimension
    int bn = blockIdx.x;         // ent tile (128 cols = 1 ent)
    int bm = blockIdx.y;         // m tile

    float acc[8][8];
#pragma unroll
    for (int i = 0; i < 8; ++i)
#pragma unroll
        for (int j = 0; j < 8; ++j) acc[i][j] = 0.f;

    int lr = tid >> 2;           // 0..63 row-in-tile for loads
    int k4 = (tid & 3) * 4;      // 0,4,8,12

    for (int kt = 0; kt < KA_ / 16; ++kt) {
        // load A tile (128 x 16): lhs[bm*128 + r][kt*16 + k4..+3]
#pragma unroll
        for (int half = 0; half < 2; ++half) {
            int m = bm * 128 + lr + half * 64;
            float4 va = *reinterpret_cast<const float4*>(&lhs[(size_t)m * KA_ + kt * 16 + k4]);
            As[k4 + 0][lr + half * 64] = va.x;
            As[k4 + 1][lr + half * 64] = va.y;
            As[k4 + 2][lr + half * 64] = va.z;
            As[k4 + 3][lr + half * 64] = va.w;
            int n = bn * 128 + lr + half * 64;
            float4 vb = *reinterpret_cast<const float4*>(&dw[(size_t)n * K1_ + kt * 16 + k4]);
            Bs[k4 + 0][lr + half * 64] = vb.x;
            Bs[k4 + 1][lr + half * 64] = vb.y;
            Bs[k4 + 2][lr + half * 64] = vb.z;
            Bs[k4 + 3][lr + half * 64] = vb.w;
        }
        __syncthreads();
#pragma unroll
        for (int k = 0; k < 16; ++k) {
            float4 a0 = *reinterpret_cast<const float4*>(&As[k][ty * 4]);
            float4 a1 = *reinterpret_cast<const float4*>(&As[k][64 + ty * 4]);
            float4 b0 = *reinterpret_cast<const float4*>(&Bs[k][tx * 4]);
            float4 b1 = *reinterpret_cast<const float4*>(&Bs[k][64 + tx * 4]);
            float am[8] = {a0.x, a0.y, a0.z, a0.w, a1.x, a1.y, a1.z, a1.w};
            float bv[8] = {b0.x, b0.y, b0.z, b0.w, b1.x, b1.y, b1.z, b1.w};
#pragma unroll
            for (int mi = 0; mi < 8; ++mi)
#pragma unroll
                for (int ni = 0; ni < 8; ++ni) acc[mi][ni] += am[mi] * bv[ni];
        }
        __syncthreads();
    }

    // Epilogue: add cls contribution, RoPE, scatter to q_ws / k_ws.
    int b = bm >> 2;                       // 512/128
    const float* ctrP = ctr + b * NOUT_ + bn * 128;
#pragma unroll
    for (int h2 = 0; h2 < 2; ++h2) {
#pragma unroll
        for (int u = 0; u < 4; ++u) {
            int mi = h2 * 4 + u;
            int s = (bm & 3) * 128 + h2 * 64 + ty * 4 + u;
            const float* tabs = rope + s * 64;  // 32 (c,s) pairs
            int i0 = tx * 2, i1 = tx * 2 + 1;
            float c0 = tabs[i0 * 2], s0 = tabs[i0 * 2 + 1];
            float c1 = tabs[i1 * 2], s1 = tabs[i1 * 2 + 1];
#pragma unroll
            for (int g = 0; g < 2; ++g) {
                int nl = g * 64 + tx * 4;
                float v0 = acc[mi][g * 4 + 0] + ctrP[nl + 0];
                float v1 = acc[mi][g * 4 + 1] + ctrP[nl + 1];
                float v2 = acc[mi][g * 4 + 2] + ctrP[nl + 2];
                float v3 = acc[mi][g * 4 + 3] + ctrP[nl + 3];
                float4 o;
                o.x = v0 * c0 - v1 * s0;
                o.y = v1 * c0 + v0 * s0;
                o.z = v2 * c1 - v3 * s1;
                o.w = v3 * c1 + v2 * s1;
                float* dst = (g == 0 ? q_ws : k_ws)
                           + (((size_t)b * ENT_ + bn) * S_ + s) * INNER_ + tx * 4;
                *reinterpret_cast<float4*>(dst) = o;
            }
        }
    }
}

// ---------------------------------------------------------------------------
// Kernel 4: logits[b][h][m][n] = (qk * pad - (1-pad)*BIG - (n<m)*BIG) * 0.125
// Per-(b,h) 512x512x64 GEMM. 128x128 tiles, K split into 2x32, 256 threads.
// Grid: (16, 52, 8) = (tile, head, batch)
// ---------------------------------------------------------------------------
__global__ __launch_bounds__(256)
void logits_k(const float* __restrict__ q_ws, const float* __restrict__ k_ws,
              const float* __restrict__ mask, float* __restrict__ out) {
    __shared__ float Qs[32][132];
    __shared__ float Ks[32][132];

    int tid = threadIdx.x;
    int tx = tid & 15;
    int ty = tid >> 4;
    int tile = blockIdx.x;
    int tm = tile >> 2, tn = tile & 3;
    int hh = blockIdx.y;
    int bb = blockIdx.z;

    float acc[8][8];
#pragma unroll
    for (int i = 0; i < 8; ++i)
#pragma unroll
        for (int j = 0; j < 8; ++j) acc[i][j] = 0.f;

    size_t panel = ((size_t)bb * ENT_ + hh) * S_;
    int r = tid >> 1;            // 0..127
    int dbs = (tid & 1) * 16;    // 0 or 16

    for (int kt = 0; kt < 2; ++kt) {
        const float* qsrc = q_ws + (panel + tm * 128 + r) * INNER_ + kt * 32 + dbs;
        const float* ksrc = k_ws + (panel + tn * 128 + r) * INNER_ + kt * 32 + dbs;
#pragma unroll
        for (int q4 = 0; q4 < 4; ++q4) {
            float4 v = *reinterpret_cast<const float4*>(qsrc + q4 * 4);
            Qs[dbs + q4 * 4 + 0][r] = v.x;
            Qs[dbs + q4 * 4 + 1][r] = v.y;
            Qs[dbs + q4 * 4 + 2][r] = v.z;
            Qs[dbs + q4 * 4 + 3][r] = v.w;
            float4 w = *reinterpret_cast<const float4*>(ksrc + q4 * 4);
            Ks[dbs + q4 * 4 + 0][r] = w.x;
            Ks[dbs + q4 * 4 + 1][r] = w.y;
            Ks[dbs + q4 * 4 + 2][r] = w.z;
            Ks[dbs + q4 * 4 + 3][r] = w.w;
        }
        __syncthreads();
#pragma unroll
        for (int k = 0; k < 32; ++k) {
            float4 a0 = *reinterpret_cast<const float4*>(&Qs[k][ty * 4]);
            float4 a1 = *reinterpret_cast<const float4*>(&Qs[k][64 + ty * 4]);
            float4 b0 = *reinterpret_cast<const float4*>(&Ks[k][tx * 4]);
            float4 b1 = *reinterpret_cast<const float4*>(&Ks[k][64 + tx * 4]);
            float am[8] = {a0.x, a0.y, a0.z, a0.w, a1.x, a1.y, a1.z, a1.w};
            float bv[8] = {b0.x, b0.y, b0.z, b0.w, b1.x, b1.y, b1.z, b1.w};
#pragma unroll
            for (int mi = 0; mi < 8; ++mi)
#pragma unroll
                for (int ni = 0; ni < 8; ++ni) acc[mi][ni] += am[mi] * bv[ni];
        }
        __syncthreads();
    }

    // Epilogue: mask + causal + scale, write float4s.
    size_t obase = ((size_t)bb * ENT_ + hh) * S_ * S_;
#pragma unroll
    for (int h2 = 0; h2 < 2; ++h2) {
#pragma unroll
        for (int u = 0; u < 4; ++u) {
            int mi = h2 * 4 + u;
            int m = tm * 128 + h2 * 64 + ty * 4 + u;
#pragma unroll
            for (int g = 0; g < 2; ++g) {
                int n0 = tn * 128 + g * 64 + tx * 4;
                float4 p4 = *reinterpret_cast<const float4*>(&mask[bb * S_ + n0]);
                float pv[4] = {p4.x, p4.y, p4.z, p4.w};
                float4 o;
                float* ov = reinterpret_cast<float*>(&o);
#pragma unroll
                for (int v = 0; v < 4; ++v) {
                    float val = acc[mi][g * 4 + v];
                    float p = pv[v];
                    val = val * p - (1.0f - p) * BIG_;
                    if (n0 + v < m) val -= BIG_;
                    ov[v] = val * 0.125f;
                }
                *reinterpret_cast<float4*>(&out[obase + (size_t)m * S_ + n0]) = o;
            }
        }
    }
}

// ---------------------------------------------------------------------------
extern "C" void kernel_launch(void* const* d_in, const int* in_sizes, int n_in,
                              void* d_out, int out_size, void* d_ws, size_t ws_size,
                              hipStream_t stream) {
    const float* lhs  = (const float*)d_in[0];
    const float* cls  = (const float*)d_in[1];
    const float* h0   = (const float*)d_in[2];
    const float* mask = (const float*)d_in[3];
    const float* wihf = (const float*)d_in[4];
    const float* whhf = (const float*)d_in[5];
    const float* bihf = (const float*)d_in[6];
    const float* bhhf = (const float*)d_in[7];
    const float* wihb = (const float*)d_in[8];
    const float* whhb = (const float*)d_in[9];
    const float* bihb = (const float*)d_in[10];
    const float* bhhb = (const float*)d_in[11];
    const float* dw   = (const float*)d_in[12];
    const float* db   = (const float*)d_in[13];
    float* out = (float*)d_out;
    float* ws  = (float*)d_ws;

    const size_t QK = (size_t)B_ * ENT_ * S_ * INNER_;   // 13,631,488
    float* q_ws    = ws;
    float* k_ws    = ws + QK;
    float* gi      = ws + 2 * QK;
    float* gh      = gi + 2 * B_ * G3_;
    float* cls_emb = gh + 2 * B_ * G3_;
    float* ctr     = cls_emb + B_ * H_;
    float* rope    = ctr + B_ * NOUT_;

    rope_table_k<<<64, 256, 0, stream>>>(rope);
    gru_gemm_k<<<576, 256, 0, stream>>>(cls, h0, wihf, whhf, bihf, bhhf,
                                        wihb, whhb, bihb, bhhb, gi, gh);
    gru_combine_k<<<24, 256, 0, stream>>>(gi, gh, h0, cls_emb);
    cls_ctr_k<<<NOUT_ / 4, 256, 0, stream>>>(cls_emb, dw, db, ctr);
    dense_gemm_k<<<dim3(ENT_, 32), 256, 0, stream>>>(lhs, dw, ctr, rope, q_ws, k_ws);
    logits_k<<<dim3(16, ENT_, B_), 256, 0, stream>>>(q_ws, k_ws, mask, out);
}

// Round 2
// 743.141 us; speedup vs baseline: 1.4990x; 1.4990x over previous
//
#include <hip/hip_runtime.h>
#include <hip/hip_bf16.h>
#include <math.h>

// Problem constants
#define B_    8
#define S_    512
#define H_    768
#define HID_  384
#define G3_   1152      // 3*HID
#define ENT_  52
#define INNER_ 64
#define NOUT_ 6656      // ENT*2*INNER
#define K1_   1536
#define KA_   768       // lhs part of K
#define BIG_  1000000000000.0f

#define TILE_BYTES 8192            // one 128x32 bf16 tile
#define A_BLK_BYTES (32u*24u*8192u)   // 6,291,456
#define B_BLK_BYTES (52u*24u*8192u)   // 10,223,616
#define QK_BLK_BYTES (8u*52u*4u*2u*8192u) // 27,262,976

typedef __attribute__((ext_vector_type(8))) short bf16x8;
typedef __attribute__((ext_vector_type(4))) float f32x4;

// RN hi + truncated lo split: x ~= hi + lo to ~2^-17 relative.
__device__ __forceinline__ void splitbf(float x, unsigned& h, unsigned& l) {
    unsigned u = __float_as_uint(x);
    unsigned t = u + 0x7fffu + ((u >> 16) & 1u);
    h = t >> 16;
    float hif = __uint_as_float(t & 0xffff0000u);
    l = __float_as_uint(x - hif) >> 16;
}

// async global->LDS, 16B per lane; LDS dest is wave-uniform base + lane*16.
__device__ __forceinline__ void gl16(const void* g, void* l) {
    __builtin_amdgcn_global_load_lds((__attribute__((address_space(1))) void*)g,
                                     (__attribute__((address_space(3))) void*)l,
                                     16, 0, 0);
}

// swizzled byte offset inside a 128x32 bf16 tile (row r, bf16 col kk)
__device__ __forceinline__ int tswz(int r, int kk) {
    return (r * 64 + kk * 2) ^ ((r & 7) << 4);
}

// ---------------------------------------------------------------------------
// RoPE cos/sin table: tab[s][i] = {cos, sin}, i in [0,32)
// ---------------------------------------------------------------------------
__global__ void rope_table_k(float* __restrict__ tab) {
    int idx = blockIdx.x * blockDim.x + threadIdx.x;
    if (idx >= S_ * 32) return;
    int s = idx >> 5;
    int i = idx & 31;
    float invf = powf(10000.0f, -2.0f * (float)i / 64.0f);
    float ang = (float)s * invf;
    tab[idx * 2 + 0] = cosf(ang);
    tab[idx * 2 + 1] = sinf(ang);
}

// ---------------------------------------------------------------------------
// Pre-convert lhs (4096 x 768 fp32) -> hi/lo bf16, tile-blocked [bm][kt][swz 8KB]
// grid 4096 blocks x 192 threads; thread t handles 4 floats at k=t*4.
// ---------------------------------------------------------------------------
__global__ void convert_lhs_k(const float* __restrict__ lhs,
                              char* __restrict__ Ah, char* __restrict__ Al) {
    int m = blockIdx.x;
    int t = threadIdx.x;
    float4 v = *reinterpret_cast<const float4*>(&lhs[(size_t)m * KA_ + t * 4]);
    unsigned h0,l0,h1,l1,h2,l2,h3,l3;
    splitbf(v.x, h0, l0); splitbf(v.y, h1, l1);
    splitbf(v.z, h2, l2); splitbf(v.w, h3, l3);
    int bm = m >> 7, r = m & 127;
    int kt = t >> 3, kk = (t & 7) * 4;
    size_t base = ((size_t)bm * 24 + kt) * TILE_BYTES;
    int off = tswz(r, kk);
    uint2 hv = make_uint2(h0 | (h1 << 16), h2 | (h3 << 16));
    uint2 lv = make_uint2(l0 | (l1 << 16), l2 | (l3 << 16));
    *reinterpret_cast<uint2*>(Ah + base + off) = hv;
    *reinterpret_cast<uint2*>(Al + base + off) = lv;
}

// ---------------------------------------------------------------------------
// Pre-convert dense_w[:, :768] -> hi/lo bf16, blocked [bn][kt][swz 8KB]
// ---------------------------------------------------------------------------
__global__ void convert_dw_k(const float* __restrict__ dw,
                             char* __restrict__ Bh, char* __restrict__ Bl) {
    int n = blockIdx.x;
    int t = threadIdx.x;
    float4 v = *reinterpret_cast<const float4*>(&dw[(size_t)n * K1_ + t * 4]);
    unsigned h0,l0,h1,l1,h2,l2,h3,l3;
    splitbf(v.x, h0, l0); splitbf(v.y, h1, l1);
    splitbf(v.z, h2, l2); splitbf(v.w, h3, l3);
    int bn = n >> 7, r = n & 127;
    int kt = t >> 3, kk = (t & 7) * 4;
    size_t base = ((size_t)bn * 24 + kt) * TILE_BYTES;
    int off = tswz(r, kk);
    uint2 hv = make_uint2(h0 | (h1 << 16), h2 | (h3 << 16));
    uint2 lv = make_uint2(l0 | (l1 << 16), l2 | (l3 << 16));
    *reinterpret_cast<uint2*>(Bh + base + off) = hv;
    *reinterpret_cast<uint2*>(Bl + base + off) = lv;
}

// ---------------------------------------------------------------------------
// GRU GEMMs (unchanged from passing baseline)
// ---------------------------------------------------------------------------
__global__ void gru_gemm_k(const float* __restrict__ cls,
                           const float* __restrict__ h0,
                           const float* __restrict__ wihf, const float* __restrict__ whhf,
                           const float* __restrict__ bihf, const float* __restrict__ bhhf,
                           const float* __restrict__ wihb, const float* __restrict__ whhb,
                           const float* __restrict__ bihb, const float* __restrict__ bhhb,
                           float* __restrict__ gi, float* __restrict__ gh) {
    int wave = blockIdx.x * (blockDim.x >> 6) + (threadIdx.x >> 6);
    int lane = threadIdx.x & 63;
    if (wave >= 2 * G3_) return;
    int dir = wave / G3_;
    int j = wave % G3_;
    const float* wih = dir ? wihb : wihf;
    const float* whh = dir ? whhb : whhf;
    const float* bih = dir ? bihb : bihf;
    const float* bhh = dir ? bhhb : bhhf;

    float ai[B_], ah[B_];
#pragma unroll
    for (int b = 0; b < B_; ++b) { ai[b] = 0.f; ah[b] = 0.f; }
    for (int k = lane; k < H_; k += 64) {
        float w = wih[j * H_ + k];
#pragma unroll
        for (int b = 0; b < B_; ++b) ai[b] += w * cls[b * H_ + k];
    }
    for (int k = lane; k < HID_; k += 64) {
        float w = whh[j * HID_ + k];
#pragma unroll
        for (int b = 0; b < B_; ++b) ah[b] += w * h0[(dir * B_ + b) * HID_ + k];
    }
#pragma unroll
    for (int off = 32; off > 0; off >>= 1) {
#pragma unroll
        for (int b = 0; b < B_; ++b) {
            ai[b] += __shfl_xor(ai[b], off);
            ah[b] += __shfl_xor(ah[b], off);
        }
    }
    if (lane == 0) {
#pragma unroll
        for (int b = 0; b < B_; ++b) {
            gi[(dir * B_ + b) * G3_ + j] = ai[b] + bih[j];
            gh[(dir * B_ + b) * G3_ + j] = ah[b] + bhh[j];
        }
    }
}

__global__ void gru_combine_k(const float* __restrict__ gi, const float* __restrict__ gh,
                              const float* __restrict__ h0, float* __restrict__ cls_emb) {
    int idx = blockIdx.x * blockDim.x + threadIdx.x;
    if (idx >= 2 * B_ * HID_) return;
    int dir = idx / (B_ * HID_);
    int r = idx % (B_ * HID_);
    int b = r / HID_;
    int h = r % HID_;
    const float* giP = gi + (dir * B_ + b) * G3_;
    const float* ghP = gh + (dir * B_ + b) * G3_;
    float ir = giP[h],        hr = ghP[h];
    float iz = giP[HID_ + h], hz = ghP[HID_ + h];
    float in_ = giP[2 * HID_ + h], hn = ghP[2 * HID_ + h];
    float rr = 1.f / (1.f + expf(-(ir + hr)));
    float z  = 1.f / (1.f + expf(-(iz + hz)));
    float n  = tanhf(in_ + rr * hn);
    float hp = h0[(dir * B_ + b) * HID_ + h];
    cls_emb[b * H_ + dir * HID_ + h] = (1.f - z) * n + z * hp;
}

__global__ void cls_ctr_k(const float* __restrict__ cls_emb,
                          const float* __restrict__ dw, const float* __restrict__ db,
                          float* __restrict__ ctr) {
    int wave = blockIdx.x * (blockDim.x >> 6) + (threadIdx.x >> 6);
    int lane = threadIdx.x & 63;
    if (wave >= NOUT_) return;
    const float* w = dw + (size_t)wave * K1_ + KA_;
    float a[B_];
#pragma unroll
    for (int b = 0; b < B_; ++b) a[b] = 0.f;
    for (int k = lane; k < H_; k += 64) {
        float ww = w[k];
#pragma unroll
        for (int b = 0; b < B_; ++b) a[b] += ww * cls_emb[b * H_ + k];
    }
#pragma unroll
    for (int off = 32; off > 0; off >>= 1) {
#pragma unroll
        for (int b = 0; b < B_; ++b) a[b] += __shfl_xor(a[b], off);
    }
    if (lane == 0) {
#pragma unroll
        for (int b = 0; b < B_; ++b) ctr[b * NOUT_ + wave] = a[b] + db[wave];
    }
}

// ---------------------------------------------------------------------------
// Dense GEMM, bf16x3 MFMA. M=4096, N=6656, K=768. 128x128 tile, BK=32,
// 4 waves (2x2), each wave 64x64 out = 4x4 frags of 16x16x32.
// Fused epilogue: +ctr, RoPE, split->bf16 hi/lo into logits-blocked layout.
// Grid (52, 32).
// ---------------------------------------------------------------------------
__global__ __launch_bounds__(256)
void dense_mfma_k(const char* __restrict__ Ahb, const char* __restrict__ Alb,
                  const char* __restrict__ Bhb, const char* __restrict__ Blb,
                  const float* __restrict__ ctr, const float* __restrict__ rope,
                  char* __restrict__ qh, char* __restrict__ ql,
                  char* __restrict__ kh, char* __restrict__ kl) {
    __shared__ __align__(16) char lds[32768];
    char* ldsAh = lds;
    char* ldsAl = lds + 8192;
    char* ldsBh = lds + 16384;
    char* ldsBl = lds + 24576;

    int tid = threadIdx.x;
    int w = tid >> 6, lane = tid & 63;
    int l15 = lane & 15, l4 = lane >> 4;
    int wr = w >> 1, wc = w & 1;
    int bn = blockIdx.x, bm = blockIdx.y;

    f32x4 acc[4][4] = {};

    const char* Ah0 = Ahb + (size_t)bm * 24 * TILE_BYTES;
    const char* Al0 = Alb + (size_t)bm * 24 * TILE_BYTES;
    const char* Bh0 = Bhb + (size_t)bn * 24 * TILE_BYTES;
    const char* Bl0 = Blb + (size_t)bn * 24 * TILE_BYTES;

    int c0 = w * 1024 + lane * 16;
    int c1 = (w + 4) * 1024 + lane * 16;
    int d0 = w * 1024, d1 = (w + 4) * 1024;

    for (int kt = 0; kt < 24; ++kt) {
        size_t tb = (size_t)kt * TILE_BYTES;
        gl16(Ah0 + tb + c0, ldsAh + d0); gl16(Ah0 + tb + c1, ldsAh + d1);
        gl16(Al0 + tb + c0, ldsAl + d0); gl16(Al0 + tb + c1, ldsAl + d1);
        gl16(Bh0 + tb + c0, ldsBh + d0); gl16(Bh0 + tb + c1, ldsBh + d1);
        gl16(Bl0 + tb + c0, ldsBl + d0); gl16(Bl0 + tb + c1, ldsBl + d1);
        __syncthreads();

        bf16x8 ah[4], al[4], bh[4], bl[4];
#pragma unroll
        for (int mi = 0; mi < 4; ++mi) {
            int row = wr * 64 + mi * 16 + l15;
            int off = (row * 64 + l4 * 16) ^ ((row & 7) << 4);
            ah[mi] = *reinterpret_cast<const bf16x8*>(ldsAh + off);
            al[mi] = *reinterpret_cast<const bf16x8*>(ldsAl + off);
        }
#pragma unroll
        for (int ni = 0; ni < 4; ++ni) {
            int col = wc * 64 + ni * 16 + l15;
            int off = (col * 64 + l4 * 16) ^ ((col & 7) << 4);
            bh[ni] = *reinterpret_cast<const bf16x8*>(ldsBh + off);
            bl[ni] = *reinterpret_cast<const bf16x8*>(ldsBl + off);
        }
#pragma unroll
        for (int mi = 0; mi < 4; ++mi)
#pragma unroll
            for (int ni = 0; ni < 4; ++ni) {
                acc[mi][ni] = __builtin_amdgcn_mfma_f32_16x16x32_bf16(ah[mi], bh[ni], acc[mi][ni], 0, 0, 0);
                acc[mi][ni] = __builtin_amdgcn_mfma_f32_16x16x32_bf16(ah[mi], bl[ni], acc[mi][ni], 0, 0, 0);
                acc[mi][ni] = __builtin_amdgcn_mfma_f32_16x16x32_bf16(al[mi], bh[ni], acc[mi][ni], 0, 0, 0);
            }
        __syncthreads();
    }

    // Epilogue. Out cols: wc==0 -> q (d=0..63), wc==1 -> k.
    int b = bm >> 2;
    int ent = bn;
    char* DH = wc ? kh : qh;
    char* DL = wc ? kl : ql;
    size_t panel = (size_t)b * ENT_ + ent;
    int tm = bm & 3;
    const float2* rope2 = reinterpret_cast<const float2*>(rope);

#pragma unroll
    for (int ni = 0; ni < 4; ++ni) {
        int d = ni * 16 + l15;               // 0..63
        float ctrv = ctr[b * NOUT_ + ent * 128 + wc * 64 + d];
        int ktq = d >> 5, kk = d & 31;
        size_t base = ((panel * 4 + tm) * 2 + ktq) * TILE_BYTES;
#pragma unroll
        for (int mi = 0; mi < 4; ++mi) {
#pragma unroll
            for (int j = 0; j < 4; ++j) {
                int r = wr * 64 + mi * 16 + l4 * 4 + j;   // row in 128-tile
                int s = tm * 128 + r;
                float v = acc[mi][ni][j] + ctrv;
                float2 cs = rope2[s * 32 + (d >> 1)];
                float p = __shfl_xor(v, 1);
                float o = (d & 1) ? fmaf(p, cs.y, v * cs.x)
                                  : fmaf(-p, cs.y, v * cs.x);
                unsigned hbits, lbits;
                splitbf(o, hbits, lbits);
                int off = tswz(r, kk);
                *reinterpret_cast<unsigned short*>(DH + base + off) = (unsigned short)hbits;
                *reinterpret_cast<unsigned short*>(DL + base + off) = (unsigned short)lbits;
            }
        }
    }
}

// ---------------------------------------------------------------------------
// Logits, bf16x3 MFMA. Per (b,h): 512x512x64. 128x128 tiles, K = 2 x 32.
// Grid (16, 52, 8), 256 threads.
// ---------------------------------------------------------------------------
__global__ __launch_bounds__(256)
void logits_mfma_k(const char* __restrict__ qh, const char* __restrict__ ql,
                   const char* __restrict__ kh, const char* __restrict__ kl,
                   const float* __restrict__ mask, float* __restrict__ out) {
    __shared__ __align__(16) char lds[32768];
    char* ldsQh = lds;
    char* ldsQl = lds + 8192;
    char* ldsKh = lds + 16384;
    char* ldsKl = lds + 24576;

    int tid = threadIdx.x;
    int w = tid >> 6, lane = tid & 63;
    int l15 = lane & 15, l4 = lane >> 4;
    int wr = w >> 1, wc = w & 1;
    int tile = blockIdx.x;
    int tm = tile >> 2, tn = tile & 3;
    int hh = blockIdx.y, bb = blockIdx.z;
    size_t panel = (size_t)bb * ENT_ + hh;

    f32x4 acc[4][4] = {};

    int c0 = w * 1024 + lane * 16;
    int c1 = (w + 4) * 1024 + lane * 16;
    int d0 = w * 1024, d1 = (w + 4) * 1024;

    for (int kt = 0; kt < 2; ++kt) {
        const char* pQh = qh + ((panel * 4 + tm) * 2 + kt) * TILE_BYTES;
        const char* pQl = ql + ((panel * 4 + tm) * 2 + kt) * TILE_BYTES;
        const char* pKh = kh + ((panel * 4 + tn) * 2 + kt) * TILE_BYTES;
        const char* pKl = kl + ((panel * 4 + tn) * 2 + kt) * TILE_BYTES;
        gl16(pQh + c0, ldsQh + d0); gl16(pQh + c1, ldsQh + d1);
        gl16(pQl + c0, ldsQl + d0); gl16(pQl + c1, ldsQl + d1);
        gl16(pKh + c0, ldsKh + d0); gl16(pKh + c1, ldsKh + d1);
        gl16(pKl + c0, ldsKl + d0); gl16(pKl + c1, ldsKl + d1);
        __syncthreads();

        bf16x8 ah[4], al[4], bh[4], bl[4];
#pragma unroll
        for (int mi = 0; mi < 4; ++mi) {
            int row = wr * 64 + mi * 16 + l15;
            int off = (row * 64 + l4 * 16) ^ ((row & 7) << 4);
            ah[mi] = *reinterpret_cast<const bf16x8*>(ldsQh + off);
            al[mi] = *reinterpret_cast<const bf16x8*>(ldsQl + off);
        }
#pragma unroll
        for (int ni = 0; ni < 4; ++ni) {
            int col = wc * 64 + ni * 16 + l15;
            int off = (col * 64 + l4 * 16) ^ ((col & 7) << 4);
            bh[ni] = *reinterpret_cast<const bf16x8*>(ldsKh + off);
            bl[ni] = *reinterpret_cast<const bf16x8*>(ldsKl + off);
        }
#pragma unroll
        for (int mi = 0; mi < 4; ++mi)
#pragma unroll
            for (int ni = 0; ni < 4; ++ni) {
                acc[mi][ni] = __builtin_amdgcn_mfma_f32_16x16x32_bf16(ah[mi], bh[ni], acc[mi][ni], 0, 0, 0);
                acc[mi][ni] = __builtin_amdgcn_mfma_f32_16x16x32_bf16(ah[mi], bl[ni], acc[mi][ni], 0, 0, 0);
                acc[mi][ni] = __builtin_amdgcn_mfma_f32_16x16x32_bf16(al[mi], bh[ni], acc[mi][ni], 0, 0, 0);
            }
        __syncthreads();
    }

    size_t obase = panel * (size_t)(S_ * S_);
#pragma unroll
    for (int ni = 0; ni < 4; ++ni) {
        int n = tn * 128 + wc * 64 + ni * 16 + l15;
        float p = mask[bb * S_ + n];
        float bigterm = (1.0f - p) * BIG_;
#pragma unroll
        for (int mi = 0; mi < 4; ++mi) {
#pragma unroll
            for (int j = 0; j < 4; ++j) {
                int m = tm * 128 + wr * 64 + mi * 16 + l4 * 4 + j;
                float val = acc[mi][ni][j];
                val = val * p - bigterm;
                if (n < m) val -= BIG_;
                out[obase + (size_t)m * S_ + n] = val * 0.125f;
            }
        }
    }
}

// ---------------------------------------------------------------------------
extern "C" void kernel_launch(void* const* d_in, const int* in_sizes, int n_in,
                              void* d_out, int out_size, void* d_ws, size_t ws_size,
                              hipStream_t stream) {
    const float* lhs  = (const float*)d_in[0];
    const float* cls  = (const float*)d_in[1];
    const float* h0   = (const float*)d_in[2];
    const float* mask = (const float*)d_in[3];
    const float* wihf = (const float*)d_in[4];
    const float* whhf = (const float*)d_in[5];
    const float* bihf = (const float*)d_in[6];
    const float* bhhf = (const float*)d_in[7];
    const float* wihb = (const float*)d_in[8];
    const float* whhb = (const float*)d_in[9];
    const float* bihb = (const float*)d_in[10];
    const float* bhhb = (const float*)d_in[11];
    const float* dw   = (const float*)d_in[12];
    const float* db   = (const float*)d_in[13];
    float* out = (float*)d_out;

    char* p = (char*)d_ws;
    char* Ahb = p;  p += A_BLK_BYTES;
    char* Alb = p;  p += A_BLK_BYTES;
    char* Bhb = p;  p += B_BLK_BYTES;
    char* Blb = p;  p += B_BLK_BYTES;
    char* qhb = p;  p += QK_BLK_BYTES;
    char* qlb = p;  p += QK_BLK_BYTES;
    char* khb = p;  p += QK_BLK_BYTES;
    char* klb = p;  p += QK_BLK_BYTES;
    float* gi      = (float*)p;           // 2*8*1152
    float* gh      = gi + 2 * B_ * G3_;
    float* cls_emb = gh + 2 * B_ * G3_;
    float* ctr     = cls_emb + B_ * H_;
    float* rope    = ctr + B_ * NOUT_;    // 512*32*2

    rope_table_k<<<64, 256, 0, stream>>>(rope);
    convert_lhs_k<<<4096, 192, 0, stream>>>(lhs, Ahb, Alb);
    convert_dw_k<<<6656, 192, 0, stream>>>(dw, Bhb, Blb);
    gru_gemm_k<<<576, 256, 0, stream>>>(cls, h0, wihf, whhf, bihf, bhhf,
                                        wihb, whhb, bihb, bhhb, gi, gh);
    gru_combine_k<<<24, 256, 0, stream>>>(gi, gh, h0, cls_emb);
    cls_ctr_k<<<NOUT_ / 4, 256, 0, stream>>>(cls_emb, dw, db, ctr);
    dense_mfma_k<<<dim3(ENT_, 32), 256, 0, stream>>>(Ahb, Alb, Bhb, Blb,
                                                     ctr, rope, qhb, qlb, khb, klb);
    logits_mfma_k<<<dim3(16, ENT_, B_), 256, 0, stream>>>(qhb, qlb, khb, klb, mask, out);
}